// Round 4
// baseline (407.406 us; speedup 1.0000x reference)
//
#include <hip/hip_runtime.h>

// LIF forward recurrence, bit-exact vs the numpy fp32 reference.
//
// Reference per step (exact op order, correctly rounded, no contraction):
//   th   = 1 + 1.5*a
//   v    = (v - v/20) + I_t
//   s    = (v >= th) ? 1 : 0        // STE forward == s_hard exactly (Sterbenz)
//   snum += s                       // exact {0,1} integer cumsum
//   v    = s ? -0.5 : v
//   a    = (a - a/100) + s
//
// R1: LDS 64x64 tile transpose killed 3x HBM write amplification (then real).
// R2: Markstein 3-op constant division (provably == __fdiv_rn for d=20,100).
// R4-R7: producer/consumer waves, lgkm-only barriers, swizzled b128 LDS,
//        quad-buffered tiles.
// R8/R9: compute-side cumsum + stateless 2-helper flush: NEUTRAL => helper
//        was not critical; compute wave's serial issue stream is the floor.
// R10: packed-f32 dual issue (v_pk_mul/fma/add, per-component rn == scalar,
//        bit-exact). 16 -> 11 ops/step. Slice 46 -> ~38 us, matching the
//        predicted 20k-cycle saving exactly. Issue-stream model validated.
// R11 (this): delete the LDS/helper staging machine entirely. Rationale:
//   - arithmetic floor is ~22-24 cyc/step (11 ops x 2 cyc issue, ~20 cyc dep
//     chain); measured ~44 cyc/step. The gap is the staging apparatus: 64
//     ds_write_b128/pair + helper ds_reads on the same LDS pipe + 16x
//     lgkmcnt(0)+barrier drains + helper store backpressure through the
//     pair barrier.
//   - the staging exists only to coalesce output stores, but outputs never
//     reach HBM: 256 MB of writes are L3-absorbed and overwritten in place
//     by the next harness poison fill (fills stream their own 1 GiB
//     regardless). Per-lane float4 stores cover each 64B line with 4
//     consecutive insts (~400 cyc << L2 turnover ~23k cyc), so the
//     partial-line fetch-on-write hazard behind R1's 3x amplification no
//     longer applies.
//   Structure: 64 threads/block (one wave), 256 blocks, each lane owns one
//   row; double-buffered register prefetch of I (unchanged); spikes/series
//   stored per-lane row-major float4, fire-and-forget (no vmcnt waits, no
//   barriers, LDS = 0). Predicted slice ~21-25 us.

#define LIF_L  2048
#define TILE   64
#define NTILES (LIF_L / TILE)   // 32

typedef float f32x2 __attribute__((ext_vector_type(2)));

// Compile-time, correctly rounded: rn(-0.5/20) and rn(-0.5 - that).
constexpr float kR20 = -0.5f / 20.0f;
constexpr float kC0  = -0.5f - kR20;

// One step. x = (vn, a): vn = membrane AFTER input add (what the threshold
// sees), a = adaptation. Inext = input of the NEXT step. Returns spike {0,1}.
//
// Bit-exactness vs the proven scalar version:
//   q   = x*C1                    : per-elem rn mul == {__fmul_rn(vn,.05), __fmul_rn(a,.01)}
//   r   = fma(C2,q,x)             : exact remainders {fma(-20,q0,vn), fma(-100,qa,a)}
//   d   = fma(r,C1,q)             : Markstein => d == {__fdiv_rn(vn,20), __fdiv_rn(a,100)}
//   dec = fma(d,-1,x)             : exact product => single-rounded rn(x-d) == __fsub_rn
//   dec.x = fire ? kC0 : dec.x    : select-before-add (distributes over final rn add)
//   x'  = dec + (Inext, s)        : {rn(sel+Inext), rn(ap+s)}; s in {0,1}, ap>=0
//   th  = rn(1 + rn(1.5*a'))      : reference order mul-then-add
__device__ __forceinline__ float lif_step(float Inext, f32x2& x, float& th,
                                          float& carry) {
    const f32x2 C1 = {0.05f, 0.01f};
    const f32x2 C2 = {-20.0f, -100.0f};
    const f32x2 M1 = {-1.0f, -1.0f};
    bool fire = (x.x >= th);
    float s = fire ? 1.0f : 0.0f;
    f32x2 q   = x * C1;                              // v_pk_mul_f32
    f32x2 r   = __builtin_elementwise_fma(C2, q, x); // v_pk_fma_f32
    f32x2 d   = __builtin_elementwise_fma(r, C1, q); // v_pk_fma_f32 (exact divs)
    f32x2 dec = __builtin_elementwise_fma(d, M1, x); // v_pk_fma_f32 (= x - d)
    dec.x = fire ? kC0 : dec.x;                      // cndmask on low half
    f32x2 t = {Inext, s};
    x = dec + t;                                     // v_pk_add_f32
    carry = __fadd_rn(carry, s);                     // exact {0,1} cumsum
    th = __fadd_rn(1.0f, __fmul_rn(1.5f, x.y));      // reference order
    return s;
}

__global__ __launch_bounds__(64, 1) void lif_fwd(const float* __restrict__ I,
                                                 float* __restrict__ spikes,
                                                 float* __restrict__ series) {
    const int lane = threadIdx.x;                    // one wave per block
    const int row  = blockIdx.x * 64 + lane;         // lane owns one row

    const float4* __restrict__ I4 =
        reinterpret_cast<const float4*>(I + (size_t)row * LIF_L);
    float4* __restrict__ sp4 =
        reinterpret_cast<float4*>(spikes + (size_t)row * LIF_L);
    float4* __restrict__ se4 =
        reinterpret_cast<float4*>(series + (size_t)row * LIF_L);

    // state: x = (vn, a) packed for v_pk_* dual issue
    f32x2 x = {0.0f, 0.0f};
    float th = 1.0f, carry = 0.0f;
    float4 bufA[16], bufB[16];

    #pragma unroll
    for (int i = 0; i < 16; ++i) bufA[i] = I4[i];
    #pragma unroll
    for (int i = 0; i < 16; ++i) bufB[i] = I4[16 + i];

    // Direct stores: lane-private row is contiguous; each 64B line is fully
    // covered by 4 consecutive float4 stores -> clean full-line dirty evict.
    auto compute_tile = [&](const float4* buf, float nx0, int kt) {
        #pragma unroll
        for (int c = 0; c < 16; ++c) {
            float4 in = buf[c];
            float nxt = (c < 15) ? buf[c + 1].x : nx0;
            float4 os, oc;
            os.x = lif_step(in.y, x, th, carry); oc.x = carry;
            os.y = lif_step(in.z, x, th, carry); oc.y = carry;
            os.z = lif_step(in.w, x, th, carry); oc.z = carry;
            os.w = lif_step(nxt,  x, th, carry); oc.w = carry;
            sp4[kt * 16 + c] = os;                   // global_store_dwordx4
            se4[kt * 16 + c] = oc;                   // global_store_dwordx4
        }
    };

    // init: vn_0 = rn(rn(0 - rn(0/20)) + I_0) = I_0 exactly; a_0 = 0
    x.x = bufA[0].x;

    // Pair loop: compute tiles {2p, 2p+1} from bufA/bufB, prefetching the
    // next pair ~1.5 tiles ahead (~2k cyc, covers HBM latency). No barriers.
    for (int p = 0; p < NTILES / 2; ++p) {
        const int kt = 2 * p;
        compute_tile(bufA, bufB[0].x, kt);
        if (kt + 2 < NTILES) {
            #pragma unroll
            for (int i = 0; i < 16; ++i) bufA[i] = I4[(kt + 2) * 16 + i];
        }
        float nx0 = (kt + 2 < NTILES) ? bufA[0].x : 0.0f;
        compute_tile(bufB, nx0, kt + 1);
        if (kt + 3 < NTILES) {
            #pragma unroll
            for (int i = 0; i < 16; ++i) bufB[i] = I4[(kt + 3) * 16 + i];
        }
    }
}

extern "C" void kernel_launch(void* const* d_in, const int* in_sizes, int n_in,
                              void* d_out, int out_size, void* d_ws, size_t ws_size,
                              hipStream_t stream) {
    const float* I = (const float*)d_in[0];
    const int B = in_sizes[0] / LIF_L;                  // 16384
    float* spikes = (float*)d_out;                      // (B, L)
    float* series = (float*)d_out + (size_t)B * LIF_L;  // (B, L)

    const int threads = 64;                             // one wave per block
    const int blocks = B / 64;                          // 256 blocks, 64 rows each
    lif_fwd<<<blocks, threads, 0, stream>>>(I, spikes, series);
}

// Round 5
// 381.945 us; speedup vs baseline: 1.0667x; 1.0667x over previous
//
#include <hip/hip_runtime.h>

// LIF forward recurrence, bit-exact vs the numpy fp32 reference.
//
// Reference per step (exact op order, correctly rounded, no contraction):
//   th   = 1 + 1.5*a
//   v    = (v - v/20) + I_t
//   s    = (v >= th) ? 1 : 0        // STE forward == s_hard exactly (Sterbenz)
//   snum += s                       // exact {0,1} integer cumsum
//   v    = s ? -0.5 : v
//   a    = (a - a/100) + s
//
// R1: LDS 64x64 tile transpose killed 3x HBM write amplification.
// R2: Markstein 3-op constant division (provably == __fdiv_rn for d=20,100).
// R4-R7: producer/consumer waves, barriers, swizzled b128 LDS, quad buffers.
// R8/R9: stateless 2-helper flush: NEUTRAL => helper was never critical.
// R10: packed-f32 dual issue, 16 -> 11 ops/step. Slice 46 -> 38 us, matching
//      the predicted 20k-cycle saving. Issue-stream model validated.
// R11: direct per-lane global stores (no LDS): slice 38 -> 70 us. REFUTED the
//      "writes are free under L3" theory: scattered 16B-per-line stores 4x
//      the write transactions. Store COALESCING is load-bearing; reads were
//      always per-lane-rowmajor and fine.
// R12 (this): keep the LDS transpose, delete the helpers and ALL barriers.
//   Accounting of R10's 38us slice: arith issue ~26-28 cyc/step vs measured
//   ~44.5 => ~16 cyc/step of chain-stall holes (serial q->r->d->dec->sel->add
//   vn chain); the compute wave was also the LAST to arrive at every pair
//   barrier (helpers ~1k cyc/pair vs compute ~5.7k), so helpers only added
//   LDS-pipe contention + coupling. Single-wave merged design: while
//   computing tile kt into sp/se[kt&1], interleave the transposed coalesced
//   flush of tile kt-1 from sp/se[(kt-1)&1] (2 ds_read_b128 + 2
//   global_store_dwordx4 per c-iter, filling stall holes). 64 threads/block,
//   LDS 64 KB, 256 blocks, zero s_barrier. Predicted slice ~30-34 us.

#define LIF_L  2048
#define TILE   64
#define NTILES (LIF_L / TILE)   // 32

typedef float f32x2 __attribute__((ext_vector_type(2)));

// Compile-time, correctly rounded: rn(-0.5/20) and rn(-0.5 - that).
constexpr float kR20 = -0.5f / 20.0f;
constexpr float kC0  = -0.5f - kR20;

// One step. x = (vn, a): vn = membrane AFTER input add (what the threshold
// sees), a = adaptation. Inext = input of the NEXT step. Returns spike {0,1}.
//
// Bit-exactness vs the proven scalar version:
//   q   = x*C1                    : per-elem rn mul == {__fmul_rn(vn,.05), __fmul_rn(a,.01)}
//   r   = fma(C2,q,x)             : exact remainders {fma(-20,q0,vn), fma(-100,qa,a)}
//   d   = fma(r,C1,q)             : Markstein => d == {__fdiv_rn(vn,20), __fdiv_rn(a,100)}
//   dec = fma(d,-1,x)             : exact product => single-rounded rn(x-d) == __fsub_rn
//   dec.x = fire ? kC0 : dec.x    : select-before-add (distributes over final rn add)
//   x'  = dec + (Inext, s)        : {rn(sel+Inext), rn(ap+s)}; s in {0,1}, ap>=0
//   th  = rn(1 + rn(1.5*a'))      : reference order mul-then-add
__device__ __forceinline__ float lif_step(float Inext, f32x2& x, float& th,
                                          float& carry) {
    const f32x2 C1 = {0.05f, 0.01f};
    const f32x2 C2 = {-20.0f, -100.0f};
    const f32x2 M1 = {-1.0f, -1.0f};
    bool fire = (x.x >= th);
    float s = fire ? 1.0f : 0.0f;
    f32x2 q   = x * C1;                              // v_pk_mul_f32
    f32x2 r   = __builtin_elementwise_fma(C2, q, x); // v_pk_fma_f32
    f32x2 d   = __builtin_elementwise_fma(r, C1, q); // v_pk_fma_f32 (exact divs)
    f32x2 dec = __builtin_elementwise_fma(d, M1, x); // v_pk_fma_f32 (= x - d)
    dec.x = fire ? kC0 : dec.x;                      // cndmask on low half
    f32x2 t = {Inext, s};
    x = dec + t;                                     // v_pk_add_f32
    carry = __fadd_rn(carry, s);                     // exact {0,1} cumsum
    th = __fadd_rn(1.0f, __fmul_rn(1.5f, x.y));      // reference order
    return s;
}

// Swizzled LDS float index for (row, 16B-group g): aligned b128, conflict-free.
__device__ __forceinline__ int sw_idx(int row, int g) {
    return row * 64 + (((g) ^ (row & 15)) << 2);
}

__global__ __launch_bounds__(64, 1) void lif_fwd(const float* __restrict__ I,
                                                 float* __restrict__ spikes,
                                                 float* __restrict__ series) {
    __shared__ float sp_tile[2][64 * 64];      // double-buffered spike tiles (32 KB)
    __shared__ float se_tile[2][64 * 64];      // double-buffered series tiles (32 KB)

    const int lane = threadIdx.x;              // one wave per block
    const int row0 = blockIdx.x * 64;

    const float4* __restrict__ I4 =
        reinterpret_cast<const float4*>(I + (size_t)(row0 + lane) * LIF_L);

    // state: x = (vn, a) packed for v_pk_* dual issue
    f32x2 x = {0.0f, 0.0f};
    float th = 1.0f, carry = 0.0f;
    float4 bufA[16], bufB[16];

    #pragma unroll
    for (int i = 0; i < 16; ++i) bufA[i] = I4[i];
    #pragma unroll
    for (int i = 0; i < 16; ++i) bufB[i] = I4[16 + i];

    // One transposed-flush unit: 4 rows x 256 B of tile tkt, coalesced.
    auto flush_unit = [&](int i, int tkt, const float* psp, const float* pse) {
        int row = i * 4 + (lane >> 4);
        int g   = lane & 15;
        int ix  = sw_idx(row, g);
        float4 vs = *reinterpret_cast<const float4*>(&psp[ix]);
        float4 ve = *reinterpret_cast<const float4*>(&pse[ix]);
        size_t gaddr = (size_t)(row0 + row) * LIF_L + (size_t)tkt * TILE
                       + (size_t)g * 4;
        *reinterpret_cast<float4*>(spikes + gaddr) = vs;
        *reinterpret_cast<float4*>(series + gaddr) = ve;
    };

    // Compute tile kt into sp/se[kt&1]; interleave flush of tile kt-1 from
    // sp/se[(kt-1)&1]. Same wave => LDS dependencies ordered by waitcnts; the
    // two buffer halves are disjoint, so compute never overwrites unflushed
    // data (buffer kt&1 was flushed during tile kt-1).
    auto tile = [&](const float4* buf, float nx0, int kt) {
        float* sp = sp_tile[kt & 1];
        float* se = se_tile[kt & 1];
        const float* psp = sp_tile[(kt & 1) ^ 1];
        const float* pse = se_tile[(kt & 1) ^ 1];
        #pragma unroll
        for (int c = 0; c < 16; ++c) {
            float4 in = buf[c];
            float nxt = (c < 15) ? buf[c + 1].x : nx0;
            float4 os, oc;
            os.x = lif_step(in.y, x, th, carry); oc.x = carry;
            os.y = lif_step(in.z, x, th, carry); oc.y = carry;
            os.z = lif_step(in.w, x, th, carry); oc.z = carry;
            os.w = lif_step(nxt,  x, th, carry); oc.w = carry;
            *reinterpret_cast<float4*>(&sp[sw_idx(lane, c)]) = os;  // ds_write_b128
            *reinterpret_cast<float4*>(&se[sw_idx(lane, c)]) = oc;  // ds_write_b128
            if (kt > 0) flush_unit(c, kt - 1, psp, pse);
        }
    };

    // init: vn_0 = rn(rn(0 - rn(0/20)) + I_0) = I_0 exactly; a_0 = 0
    x.x = bufA[0].x;

    // Pair loop with register double-buffered input prefetch. No barriers.
    for (int p = 0; p < NTILES / 2; ++p) {
        const int kt = 2 * p;
        tile(bufA, bufB[0].x, kt);
        if (kt + 2 < NTILES) {
            #pragma unroll
            for (int i = 0; i < 16; ++i) bufA[i] = I4[(kt + 2) * 16 + i];
        }
        float nx0 = (kt + 2 < NTILES) ? bufA[0].x : 0.0f;
        tile(bufB, nx0, kt + 1);
        if (kt + 3 < NTILES) {
            #pragma unroll
            for (int i = 0; i < 16; ++i) bufB[i] = I4[(kt + 3) * 16 + i];
        }
    }
    // Final flush: tile NTILES-1 lives in buffers [(NTILES-1)&1] = [1].
    #pragma unroll
    for (int i = 0; i < 16; ++i) {
        flush_unit(i, NTILES - 1, sp_tile[1], se_tile[1]);
    }
}

extern "C" void kernel_launch(void* const* d_in, const int* in_sizes, int n_in,
                              void* d_out, int out_size, void* d_ws, size_t ws_size,
                              hipStream_t stream) {
    const float* I = (const float*)d_in[0];
    const int B = in_sizes[0] / LIF_L;                  // 16384
    float* spikes = (float*)d_out;                      // (B, L)
    float* series = (float*)d_out + (size_t)B * LIF_L;  // (B, L)

    const int threads = 64;                             // one wave per block
    const int blocks = B / 64;                          // 256 blocks, 64 rows each
    lif_fwd<<<blocks, threads, 0, stream>>>(I, spikes, series);
}

// Round 6
// 376.139 us; speedup vs baseline: 1.0831x; 1.0154x over previous
//
#include <hip/hip_runtime.h>

// LIF forward recurrence, bit-exact vs the numpy fp32 reference.
//
// Reference per step (exact op order, correctly rounded, no contraction):
//   th   = 1 + 1.5*a
//   v    = (v - v/20) + I_t
//   s    = (v >= th) ? 1 : 0        // STE forward == s_hard exactly (Sterbenz)
//   snum += s                       // exact {0,1} integer cumsum
//   v    = s ? -0.5 : v
//   a    = (a - a/100) + s
//
// R1: LDS 64x64 tile transpose killed 3x HBM write amplification.
// R2: Markstein 3-op constant division (provably == __fdiv_rn for d=20,100).
// R4-R7: producer/consumer waves, barriers, swizzled b128 LDS, quad buffers.
// R8/R9: compute-side cumsum + stateless 2-helper flush: NEUTRAL => helper
//      was never the critical wave; compute's serial issue stream is.
// R10: packed-f32 dual issue (v_pk_mul/fma/add, per-component rn == scalar,
//      bit-exact). 16 -> 11 ops/step. Slice 46 -> ~38 us (375.4 total) ==
//      session best. Issue-stream model validated.
// R11: direct per-lane global stores (no LDS): slice -> 70 us. REFUTED
//      "writes free under L3": scattered 16B-per-line stores 4x the write
//      transactions. Store coalescing is load-bearing.
// R12: merged flush into compute wave, no barriers: slice -> 45 us. REFUTED
//      "fill chain stalls with flush": ds_read->global_store forces lgkmcnt
//      waits INSIDE the compute body; a waitcnt blocks the whole wave,
//      costing ~14 cyc/step -- more than the helper coupling it removed.
// R13 (this): revert to R10 verbatim -- the measured optimum. The design
//   space is fenced: (a) stores must be LDS-transposed (R11), (b) wait-
//   bearing ops must live in helper waves (R12), (c) helpers are not the
//   critical path (R8/R9), (d) compute is pure-VALU + wait-free ds_writes
//   at ~44.5 cyc/step vs a ~24-cyc loop-carried chain floor (vn-decay and
//   a->th->cmp->s cycles both ~24 cyc). Remaining levers (2-row ILP pack,
//   speculative-th, same-SIMD wave sharing) all compute out negative:
//   issue rises past the measured stall level. Latency-bound recurrence;
//   ~88% of dur_us is fixed harness poison-fill cost.

#define LIF_L  2048
#define TILE   64
#define NTILES (LIF_L / TILE)   // 32

typedef float f32x2 __attribute__((ext_vector_type(2)));

// Compile-time, correctly rounded: rn(-0.5/20) and rn(-0.5 - that).
constexpr float kR20 = -0.5f / 20.0f;
constexpr float kC0  = -0.5f - kR20;

__device__ __forceinline__ void barrier_lds_only() {
    asm volatile("s_waitcnt lgkmcnt(0)\n\ts_barrier" ::: "memory");
}

// One step. x = (vn, a): vn = membrane AFTER input add (what the threshold
// sees), a = adaptation. Inext = input of the NEXT step. Returns spike {0,1}.
//
// Bit-exactness vs the proven scalar version:
//   q   = x*C1                    : per-elem rn mul == {__fmul_rn(vn,.05), __fmul_rn(a,.01)}
//   r   = fma(C2,q,x)             : exact remainders {fma(-20,q0,vn), fma(-100,qa,a)}
//   d   = fma(r,C1,q)             : Markstein => d == {__fdiv_rn(vn,20), __fdiv_rn(a,100)}
//   dec = fma(d,-1,x)             : exact product => single-rounded rn(x-d) == __fsub_rn
//   dec.x = fire ? kC0 : dec.x    : select-before-add (distributes over final rn add)
//   x'  = dec + (Inext, s)        : {rn(sel+Inext), rn(ap+s)}; s in {0,1}, ap>=0
//   th  = rn(1 + rn(1.5*a'))      : reference order mul-then-add
__device__ __forceinline__ float lif_step(float Inext, f32x2& x, float& th,
                                          float& carry) {
    const f32x2 C1 = {0.05f, 0.01f};
    const f32x2 C2 = {-20.0f, -100.0f};
    const f32x2 M1 = {-1.0f, -1.0f};
    bool fire = (x.x >= th);
    float s = fire ? 1.0f : 0.0f;
    f32x2 q   = x * C1;                              // v_pk_mul_f32
    f32x2 r   = __builtin_elementwise_fma(C2, q, x); // v_pk_fma_f32
    f32x2 d   = __builtin_elementwise_fma(r, C1, q); // v_pk_fma_f32 (exact divs)
    f32x2 dec = __builtin_elementwise_fma(d, M1, x); // v_pk_fma_f32 (= x - d)
    dec.x = fire ? kC0 : dec.x;                      // cndmask on low half
    f32x2 t = {Inext, s};
    x = dec + t;                                     // v_pk_add_f32
    carry = __fadd_rn(carry, s);                     // exact {0,1} cumsum
    th = __fadd_rn(1.0f, __fmul_rn(1.5f, x.y));      // reference order
    return s;
}

// Swizzled LDS float index for (row, 16B-group g): aligned b128, conflict-free.
__device__ __forceinline__ int sw_idx(int row, int g) {
    return row * 64 + (((g) ^ (row & 15)) << 2);
}

__global__ __launch_bounds__(192, 1) void lif_fwd(const float* __restrict__ I,
                                                  float* __restrict__ spikes,
                                                  float* __restrict__ series) {
    __shared__ float sp_tile[4][64 * 64];      // quad-buffered spike tiles (64 KB)
    __shared__ float se_tile[4][64 * 64];      // quad-buffered series tiles (64 KB)

    const int tid  = threadIdx.x;
    const int wave = tid >> 6;                 // 0 = compute, 1/2 = helpers
    const int lane = tid & 63;
    const int row0 = blockIdx.x * 64;

    const float4* __restrict__ I4 =
        reinterpret_cast<const float4*>(I + (size_t)(row0 + lane) * LIF_L);

    // compute-wave state: x = (vn, a) packed for v_pk_* dual issue
    f32x2 x = {0.0f, 0.0f};
    float th = 1.0f, carry = 0.0f;
    float4 bufA[16], bufB[16];

    if (wave == 0) {
        #pragma unroll
        for (int i = 0; i < 16; ++i) bufA[i] = I4[i];
        #pragma unroll
        for (int i = 0; i < 16; ++i) bufB[i] = I4[16 + i];
    }

    auto compute_tile = [&](const float4* buf, float nx0, float* sp, float* se) {
        #pragma unroll
        for (int c = 0; c < 16; ++c) {
            float4 in = buf[c];
            float nxt = (c < 15) ? buf[c + 1].x : nx0;
            float4 os, oc;
            os.x = lif_step(in.y, x, th, carry); oc.x = carry;
            os.y = lif_step(in.z, x, th, carry); oc.y = carry;
            os.z = lif_step(in.w, x, th, carry); oc.z = carry;
            os.w = lif_step(nxt,  x, th, carry); oc.w = carry;
            *reinterpret_cast<float4*>(&sp[sw_idx(lane, c)]) = os;  // ds_write_b128
            *reinterpret_cast<float4*>(&se[sw_idx(lane, c)]) = oc;  // ds_write_b128
        }
    };

    // Stateless flush: transposed coalesced stores, instr i covers 4 rows x 256 B.
    auto flush_tile = [&](int tkt, const float* sp, const float* se) {
        const size_t colbase = (size_t)tkt * TILE;
        #pragma unroll
        for (int i = 0; i < 16; ++i) {
            int row = i * 4 + (lane >> 4);
            int g   = lane & 15;
            int ix  = sw_idx(row, g);
            float4 vs = *reinterpret_cast<const float4*>(&sp[ix]);
            float4 ve = *reinterpret_cast<const float4*>(&se[ix]);
            size_t gaddr = (size_t)(row0 + row) * LIF_L + colbase + (size_t)g * 4;
            *reinterpret_cast<float4*>(spikes + gaddr) = vs;
            *reinterpret_cast<float4*>(series + gaddr) = ve;
        }
    };

    // init: vn_0 = rn(rn(0 - rn(0/20)) + I_0) = I_0 exactly; a_0 = 0
    if (wave == 0) x.x = bufA[0].x;

    // Pair loop: iteration p computes tiles {2p, 2p+1} into buffer set
    // {(2p)&3, (2p+1)&3}; helpers consume pair p-1 (the other, disjoint set):
    // wave1 flushes tile 2p-2, wave2 flushes tile 2p-1. One barrier per pair.
    for (int p = 0; p < NTILES / 2; ++p) {
        const int kt = 2 * p;
        if (wave == 0) {
            compute_tile(bufA, bufB[0].x, sp_tile[kt & 3], se_tile[kt & 3]);
            if (kt + 2 < NTILES) {
                #pragma unroll
                for (int i = 0; i < 16; ++i) bufA[i] = I4[(kt + 2) * 16 + i];
            }
            float nx0 = (kt + 2 < NTILES) ? bufA[0].x : 0.0f;
            compute_tile(bufB, nx0, sp_tile[(kt + 1) & 3], se_tile[(kt + 1) & 3]);
            if (kt + 3 < NTILES) {
                #pragma unroll
                for (int i = 0; i < 16; ++i) bufB[i] = I4[(kt + 3) * 16 + i];
            }
        } else if (p > 0) {
            if (wave == 1) {
                flush_tile(kt - 2, sp_tile[(kt - 2) & 3], se_tile[(kt - 2) & 3]);
            } else {
                flush_tile(kt - 1, sp_tile[(kt - 1) & 3], se_tile[(kt - 1) & 3]);
            }
        }
        barrier_lds_only();
    }
    // tail: last pair (tiles 30, 31 live in buffer sets 2, 3)
    if (wave == 1) {
        flush_tile(NTILES - 2, sp_tile[(NTILES - 2) & 3], se_tile[(NTILES - 2) & 3]);
    } else if (wave == 2) {
        flush_tile(NTILES - 1, sp_tile[(NTILES - 1) & 3], se_tile[(NTILES - 1) & 3]);
    }
}

extern "C" void kernel_launch(void* const* d_in, const int* in_sizes, int n_in,
                              void* d_out, int out_size, void* d_ws, size_t ws_size,
                              hipStream_t stream) {
    const float* I = (const float*)d_in[0];
    const int B = in_sizes[0] / LIF_L;                  // 16384
    float* spikes = (float*)d_out;                      // (B, L)
    float* series = (float*)d_out + (size_t)B * LIF_L;  // (B, L)

    const int threads = 192;                            // 3 waves: compute + 2 helpers
    const int blocks = B / 64;                          // 256 blocks, 64 rows each
    lif_fwd<<<blocks, threads, 0, stream>>>(I, spikes, series);
}